// Round 7
// baseline (204.076 us; speedup 1.0000x reference)
//
#include <hip/hip_runtime.h>
#include <hip/hip_bf16.h>

typedef __attribute__((ext_vector_type(8))) short bshort8;      // 8 bf16 (4 VGPR) MFMA frag
typedef __attribute__((ext_vector_type(4))) float f32x4;        // MFMA accumulator
typedef __attribute__((ext_vector_type(4))) float vfloat4;
typedef __attribute__((ext_vector_type(4))) unsigned int vuint4;
typedef __attribute__((ext_vector_type(2))) unsigned int vuint2;

__device__ __forceinline__ unsigned short f2bf(float f) {
    union { float f; unsigned u; } v; v.f = f;
    unsigned u = v.u;
    u += 0x7fffu + ((u >> 16) & 1u);   // round-to-nearest-even
    return (unsigned short)(u >> 16);
}

// ---------------------------------------------------------------------------
// Generic batched C = A[M][K] @ Bt[N][K]^T (bf16), MFMA 16x16x32.
// Tile: BM=64, BN=64, BK=32; 4 waves 2x2. EPI: 0 = fp32 store, 1 = bf16 store
// ---------------------------------------------------------------------------
template<int EPI>
__global__ __launch_bounds__(256)
void gemm_bt(const unsigned short* __restrict__ Av, const unsigned short* __restrict__ Btv,
             void* __restrict__ Cv,
             int M, int N, int K,
             long long aB, long long bB, long long cB)
{
    __shared__ __align__(128) char sA[64 * 64];   // 64 rows x 32 bf16 (64B/row)
    __shared__ __align__(128) char sB[64 * 64];

    const int b    = blockIdx.z;
    const int tid  = threadIdx.x;
    const int bRow = blockIdx.y << 6;
    const int bCol = blockIdx.x << 6;
    const int wid  = tid >> 6, lane = tid & 63;
    const int wr   = wid >> 1, wc   = wid & 1;
    const int r16  = lane & 15, kg  = lane >> 4;
    const int srow = tid >> 2,  skc = tid & 3;     // staging: row 0..63, k-chunk 0..3

    const unsigned short* A  = Av  + (size_t)aB * b;
    const unsigned short* Bt = Btv + (size_t)bB * b;

    f32x4 acc[2][2] = {};

    const size_t aRowBase = (size_t)(bRow + srow) * K + skc * 8;
    const size_t bRowBase = (size_t)(bCol + srow) * K + skc * 8;
    const unsigned swW = ((((unsigned)srow) << 6) | (((unsigned)skc) << 4))
                         ^ ((((unsigned)srow) & 7u) << 4);

    for (int k0 = 0; k0 < K; k0 += 32) {
        vuint4 apack = *(const vuint4*)(A  + aRowBase + k0);
        vuint4 bpack = *(const vuint4*)(Bt + bRowBase + k0);
        *(vuint4*)(sA + swW) = apack;
        *(vuint4*)(sB + swW) = bpack;
        __syncthreads();

        bshort8 af[2], bfr[2];
        #pragma unroll
        for (int mi = 0; mi < 2; mi++) {
            unsigned row = (unsigned)(wr * 32 + mi * 16 + r16);
            unsigned off = ((row << 6) | (((unsigned)kg) << 4)) ^ ((row & 7u) << 4);
            af[mi] = *(const bshort8*)(sA + off);
        }
        #pragma unroll
        for (int ni = 0; ni < 2; ni++) {
            unsigned col = (unsigned)(wc * 32 + ni * 16 + r16);
            unsigned off = ((col << 6) | (((unsigned)kg) << 4)) ^ ((col & 7u) << 4);
            bfr[ni] = *(const bshort8*)(sB + off);
        }
        #pragma unroll
        for (int mi = 0; mi < 2; mi++)
            #pragma unroll
            for (int ni = 0; ni < 2; ni++)
                acc[mi][ni] = __builtin_amdgcn_mfma_f32_16x16x32_bf16(
                                  af[mi], bfr[ni], acc[mi][ni], 0, 0, 0);
        __syncthreads();
    }

    // D frag: col = lane&15, row = (lane>>4)*4 + r  [verified layout]
    #pragma unroll
    for (int mi = 0; mi < 2; mi++) {
        const int row0 = bRow + wr * 32 + mi * 16 + kg * 4;
        #pragma unroll
        for (int ni = 0; ni < 2; ni++) {
            const int col = bCol + wc * 32 + ni * 16 + r16;
            #pragma unroll
            for (int r = 0; r < 4; r++) {
                const int row = row0 + r;
                float x = acc[mi][ni][r];
                const size_t ci = (size_t)cB * b + (size_t)row * N + col;
                if constexpr (EPI == 0) ((float*)Cv)[ci] = x;
                else                    ((unsigned short*)Cv)[ci] = f2bf(x);
            }
        }
    }
}

// ---------------------------------------------------------------------------
// Flash attention v5: swapped QK^T -> wave-private P, 1 barrier/chunk.
// 8 waves x 16 q-rows each (Q-tile 128). Per chunk (64 keys):
//   QK: sacc[kt] = mfma(g_tile, f_tile)  -> D[key][q], q = lane&15 (private)
//   exp+pack -> 4x ds_write_b64 into wave-private P rows (own f region)
//   PV: full 256-n for own 16 q: 32 MFMA, A = private P frags
// KV staging double-buffered, issue-early/write-late. setprio around MFMA.
// LDS 96.5KB, 1 block/CU, waves drift (no MFMA/VALU lockstep).
// ---------------------------------------------------------------------------
__global__ __launch_bounds__(512)
void flash_attn(const float* __restrict__ x,
                const unsigned short* __restrict__ wft,
                const unsigned short* __restrict__ gb,
                const unsigned short* __restrict__ ht,
                unsigned short* __restrict__ yb)
{
    __shared__ __align__(128) char sS[128 * 128];       // f tile / per-wave P (16KB)
    __shared__ __align__(128) char sG[2][64 * 128];     // g dbuf (16KB)
    __shared__ __align__(128) char sH[2][256 * 128];    // ht dbuf (64KB)

    const int tid = threadIdx.x;
    const int bid = blockIdx.x;
    const int b   = bid & 7;            // batch == XCD slot (L2-local KV)
    const int q0  = (bid >> 3) << 7;    // 128 q-rows per block
    const int wid = tid >> 6, lane = tid & 63;
    const int r16 = lane & 15, kg = lane >> 4;

    const float*          xB = x  + ((size_t)b * 4096 + q0) * 512;
    const unsigned short* gB = gb + (size_t)b * 1024 * 64;
    const unsigned short* hB = ht + (size_t)b * 256 * 1024;

    char* const sG0 = sG[0];
    char* const sH0 = sH[0];

    // ================= f = x @ wf  (128 x 64, K=512, BK=64) =================
    f32x4 facc[4] = {};
    {
        const int xrow = tid >> 2, xc = tid & 3;     // x: 128 rows, 4 thr/row
        const int wrow = tid >> 3, wkc = tid & 7;    // wf: 64 rows, 8 thr/row
        const int frow = wid << 4;                   // wave's 16 f-rows
        for (int k0 = 0; k0 < 512; k0 += 64) {
            {   // stage x chunk [128][64] -> sH0 (bf16, swizzled): 2 vuint4/thread
                const float* p = xB + (size_t)xrow * 512 + k0 + xc * 16;
                #pragma unroll
                for (int j = 0; j < 2; j++) {
                    vfloat4 a0 = *(const vfloat4*)(p + j * 8);
                    vfloat4 a1 = *(const vfloat4*)(p + j * 8 + 4);
                    vuint4 w;
                    w[0] = (unsigned)f2bf(a0[0]) | ((unsigned)f2bf(a0[1]) << 16);
                    w[1] = (unsigned)f2bf(a0[2]) | ((unsigned)f2bf(a0[3]) << 16);
                    w[2] = (unsigned)f2bf(a1[0]) | ((unsigned)f2bf(a1[1]) << 16);
                    w[3] = (unsigned)f2bf(a1[2]) | ((unsigned)f2bf(a1[3]) << 16);
                    unsigned off = ((unsigned)xrow * 128 + (unsigned)(xc * 32 + j * 16))
                                   ^ (((unsigned)xrow & 7u) << 4);
                    *(vuint4*)(sH0 + off) = w;
                }
            }
            {   // stage wf chunk [64][64] -> sG0: 1 vuint4/thread
                vuint4 v = *(const vuint4*)(wft + (size_t)wrow * 512 + k0 + wkc * 8);
                unsigned off = ((unsigned)wrow * 128 + (unsigned)wkc * 16)
                               ^ (((unsigned)wrow & 7u) << 4);
                *(vuint4*)(sG0 + off) = v;
            }
            __syncthreads();

            bshort8 ax[2];
            {
                unsigned row = (unsigned)(frow + r16);
                unsigned base = row * 128, sw = (row & 7u) << 4;
                ax[0] = *(const bshort8*)(sH0 + ((base + (unsigned)kg * 16) ^ sw));
                ax[1] = *(const bshort8*)(sH0 + ((base + 64 + (unsigned)kg * 16) ^ sw));
            }
            #pragma unroll
            for (int ni = 0; ni < 4; ni++) {
                unsigned col = (unsigned)(ni * 16 + r16);
                unsigned base = col * 128, sw = (col & 7u) << 4;
                bshort8 b0 = *(const bshort8*)(sG0 + ((base + (unsigned)kg * 16) ^ sw));
                bshort8 b1 = *(const bshort8*)(sG0 + ((base + 64 + (unsigned)kg * 16) ^ sw));
                facc[ni] = __builtin_amdgcn_mfma_f32_16x16x32_bf16(ax[0], b0, facc[ni], 0, 0, 0);
                facc[ni] = __builtin_amdgcn_mfma_f32_16x16x32_bf16(ax[1], b1, facc[ni], 0, 0, 0);
            }
            __syncthreads();
        }

        // redistribute f: C-layout acc -> sS rows [wid*16, wid*16+16) (own region)
        const int frow2 = wid << 4;
        #pragma unroll
        for (int ni = 0; ni < 4; ni++) {
            const unsigned col = (unsigned)(ni * 16 + r16);
            #pragma unroll
            for (int r = 0; r < 4; r++) {
                unsigned row = (unsigned)(frow2 + kg * 4 + r);
                unsigned off = (row * 128 + col * 2) ^ ((row & 7u) << 4);
                *(unsigned short*)(sS + off) = f2bf(facc[ni][r]);
            }
        }
    }

    // ================= prologue: stage chunk 0 into buf 0 =================
    const int kc = tid & 7, n0 = tid >> 3;           // staging: 64 rows, 8 thr/row
    const unsigned gOff  = ((unsigned)n0 * 128 + (unsigned)kc * 16) ^ (((unsigned)n0 & 7u) << 4);
    const unsigned hOff0 = gOff;                      // (n0+64k)&7 == n0&7 -> +k*8192

    vuint4 gR, hR0, hR1, hR2, hR3;
    gR  = *(const vuint4*)(gB + (size_t)n0 * 64 + kc * 8);
    hR0 = *(const vuint4*)(hB + (size_t)(n0      ) * 1024 + kc * 8);
    hR1 = *(const vuint4*)(hB + (size_t)(n0 +  64) * 1024 + kc * 8);
    hR2 = *(const vuint4*)(hB + (size_t)(n0 + 128) * 1024 + kc * 8);
    hR3 = *(const vuint4*)(hB + (size_t)(n0 + 192) * 1024 + kc * 8);
    // safe: f-loop's trailing barrier means all waves finished reading sG0/sH0
    *(vuint4*)(sG0 + gOff)               = gR;
    *(vuint4*)(sH0 + hOff0)              = hR0;
    *(vuint4*)(sH0 + hOff0 +     8192)   = hR1;
    *(vuint4*)(sH0 + hOff0 + 2 * 8192)   = hR2;
    *(vuint4*)(sH0 + hOff0 + 3 * 8192)   = hR3;
    __syncthreads();                      // buf0 visible (sS region is per-wave)

    // f B-frags for QK (own 16 q-rows), held in registers
    char* const sP = sS + (wid << 11);    // per-wave 2KB region == own f rows
    bshort8 af[2];
    {
        unsigned base = (unsigned)r16 * 128, sw = ((unsigned)r16 & 7u) << 4;
        af[0] = *(const bshort8*)(sP + ((base + (unsigned)kg * 16) ^ sw));
        af[1] = *(const bshort8*)(sP + ((base + 64 + (unsigned)kg * 16) ^ sw));
    }

    // ================= KV loop (1 barrier/chunk, waves drift) =================
    f32x4 yacc[16] = {};
    float psum = 0.f;

    for (int c = 0; c < 16; c++) {
        const int cur = c & 1;
        char* const sGc = sG[cur];
        char* const sHc = sH[cur];

        // issue chunk c+1 loads early — fly under QK+exp+PV
        if (c < 15) {
            const int kv1 = (c + 1) << 6;
            gR  = *(const vuint4*)(gB + (size_t)(kv1 + n0) * 64 + kc * 8);
            hR0 = *(const vuint4*)(hB + (size_t)(n0      ) * 1024 + kv1 + kc * 8);
            hR1 = *(const vuint4*)(hB + (size_t)(n0 +  64) * 1024 + kv1 + kc * 8);
            hR2 = *(const vuint4*)(hB + (size_t)(n0 + 128) * 1024 + kv1 + kc * 8);
            hR3 = *(const vuint4*)(hB + (size_t)(n0 + 192) * 1024 + kv1 + kc * 8);
        }

        // ---- QK (swapped): sacc[kt] = g_tile(kt) x f -> S^T[key][q] ----
        f32x4 sacc[4] = {};
        {
            __builtin_amdgcn_s_setprio(1);
            #pragma unroll
            for (int kt = 0; kt < 4; kt++) {
                unsigned row = (unsigned)(kt * 16 + r16);
                unsigned base = row * 128, sw = (row & 7u) << 4;
                bshort8 g0 = *(const bshort8*)(sGc + ((base + (unsigned)kg * 16) ^ sw));
                bshort8 g1 = *(const bshort8*)(sGc + ((base + 64 + (unsigned)kg * 16) ^ sw));
                sacc[kt] = __builtin_amdgcn_mfma_f32_16x16x32_bf16(g0, af[0], sacc[kt], 0, 0, 0);
                sacc[kt] = __builtin_amdgcn_mfma_f32_16x16x32_bf16(g1, af[1], sacc[kt], 0, 0, 0);
            }
            __builtin_amdgcn_s_setprio(0);
        }

        // ---- exp, psum, pack 4 bf16 -> 1 ds_write_b64 per key-tile (private) ----
        #pragma unroll
        for (int kt = 0; kt < 4; kt++) {
            float e0 = __expf(sacc[kt][0]);
            float e1 = __expf(sacc[kt][1]);
            float e2 = __expf(sacc[kt][2]);
            float e3 = __expf(sacc[kt][3]);
            psum += (e0 + e1) + (e2 + e3);
            vuint2 pk;
            pk[0] = (unsigned)f2bf(e0) | ((unsigned)f2bf(e1) << 16);
            pk[1] = (unsigned)f2bf(e2) | ((unsigned)f2bf(e3) << 16);
            // P[q=r16][key = kt*16 + kg*4 + 0..3]
            unsigned off = ((unsigned)r16 * 128 + (unsigned)(kt * 32 + kg * 8))
                           ^ (((unsigned)r16 & 7u) << 4);
            *(vuint2*)(sP + off) = pk;
        }

        // ---- PV: yacc[ni] += P(own) x ht, full 256-n ----
        bshort8 pa0, pa1;
        {
            unsigned base = (unsigned)r16 * 128, sw = ((unsigned)r16 & 7u) << 4;
            pa0 = *(const bshort8*)(sP + ((base + (unsigned)kg * 16) ^ sw));
            pa1 = *(const bshort8*)(sP + ((base + 64 + (unsigned)kg * 16) ^ sw));
        }
        __builtin_amdgcn_s_setprio(1);
        #pragma unroll
        for (int ni = 0; ni < 16; ni++) {
            unsigned col = (unsigned)(ni * 16 + r16);
            unsigned base = col * 128, sw = (col & 7u) << 4;
            bshort8 b0 = *(const bshort8*)(sHc + ((base + (unsigned)kg * 16) ^ sw));
            bshort8 b1 = *(const bshort8*)(sHc + ((base + 64 + (unsigned)kg * 16) ^ sw));
            yacc[ni] = __builtin_amdgcn_mfma_f32_16x16x32_bf16(pa0, b0, yacc[ni], 0, 0, 0);
            yacc[ni] = __builtin_amdgcn_mfma_f32_16x16x32_bf16(pa1, b1, yacc[ni], 0, 0, 0);
        }
        __builtin_amdgcn_s_setprio(0);

        // write chunk c+1 into the inactive buffer (its readers passed the
        // previous barrier; visibility via the barrier below)
        if (c < 15) {
            char* const sGn = sG[cur ^ 1];
            char* const sHn = sH[cur ^ 1];
            *(vuint4*)(sGn + gOff)             = gR;
            *(vuint4*)(sHn + hOff0)            = hR0;
            *(vuint4*)(sHn + hOff0 +     8192) = hR1;
            *(vuint4*)(sHn + hOff0 + 2 * 8192) = hR2;
            *(vuint4*)(sHn + hOff0 + 3 * 8192) = hR3;
        }
        __syncthreads();
    }

    // ---- rowsum: psum[lane] covers q=r16, keys (kg groups x chunks) ----
    psum += __shfl_xor(psum, 16, 64);
    psum += __shfl_xor(psum, 32, 64);
    const float rinv = 1.0f / psum;          // valid in every lane for q=r16

    // ---- normalize + store y: y[wid*16 + kg*4 + r][ni*16 + r16] ----
    unsigned short* yB = yb + ((size_t)b * 4096 + q0 + wid * 16) * 256;
    float rv[4];
    #pragma unroll
    for (int r = 0; r < 4; r++)
        rv[r] = __shfl(rinv, kg * 4 + r, 16);   // rinv of q = kg*4+r
    #pragma unroll
    for (int r = 0; r < 4; r++) {
        const int row = kg * 4 + r;
        #pragma unroll
        for (int ni = 0; ni < 16; ni++) {
            const int col = ni * 16 + r16;
            yB[(size_t)row * 256 + col] = f2bf(yacc[ni][r] * rv[r]);
        }
    }
}

// 2x2 avgpool NHWC fp32 -> bf16, 4 channels per thread
__global__ __launch_bounds__(256)
void pool2(const float* __restrict__ x, unsigned short* __restrict__ xp)
{
    const int t  = blockIdx.x * 256 + threadIdx.x;   // 8*32*32*128 threads
    const int c4 = t & 127;
    const int j  = (t >> 7) & 31;
    const int i  = (t >> 12) & 31;
    const int b  = t >> 17;
    const float* p = x + ((((size_t)b * 64 + 2 * i) * 64) + 2 * j) * 512 + c4 * 4;
    vfloat4 a0 = *(const vfloat4*)p;
    vfloat4 a1 = *(const vfloat4*)(p + 512);
    vfloat4 a2 = *(const vfloat4*)(p + 64 * 512);
    vfloat4 a3 = *(const vfloat4*)(p + 64 * 512 + 512);
    float r0 = 0.25f * (a0[0] + a1[0] + a2[0] + a3[0]);
    float r1 = 0.25f * (a0[1] + a1[1] + a2[1] + a3[1]);
    float r2 = 0.25f * (a0[2] + a1[2] + a2[2] + a3[2]);
    float r3 = 0.25f * (a0[3] + a1[3] + a2[3] + a3[3]);
    vuint2 o;
    o[0] = (unsigned)f2bf(r0) | ((unsigned)f2bf(r1) << 16);
    o[1] = (unsigned)f2bf(r2) | ((unsigned)f2bf(r3) << 16);
    *(vuint2*)(xp + (size_t)t * 4) = o;
}

// All 4 weight transposes (fp32 [K][N] -> bf16 [N][K]) in ONE kernel.
__global__ __launch_bounds__(256)
void wprep(const float* __restrict__ wf, const float* __restrict__ wg,
           const float* __restrict__ wh, const float* __restrict__ wo,
           unsigned short* __restrict__ wf_t, unsigned short* __restrict__ wg_t,
           unsigned short* __restrict__ wh_t, unsigned short* __restrict__ wo_t)
{
    __shared__ float tile[32][33];
    int t = blockIdx.x;
    const float* in; unsigned short* out; int K, N;
    if (t < 32)       { in = wf; out = wf_t; K = 512; N = 64;  }
    else if (t < 64)  { in = wg; out = wg_t; K = 512; N = 64;  t -= 32;  }
    else if (t < 192) { in = wh; out = wh_t; K = 512; N = 256; t -= 64;  }
    else              { in = wo; out = wo_t; K = 256; N = 512; t -= 192; }
    const int ntN = N >> 5;
    const int tk = (t / ntN) << 5, tn = (t % ntN) << 5;
    const int tx = threadIdx.x & 31, ty = threadIdx.x >> 5;   // ty 0..7
    #pragma unroll
    for (int s = 0; s < 4; s++)
        tile[ty + s * 8][tx] = in[(size_t)(tk + ty + s * 8) * N + tn + tx];
    __syncthreads();
    #pragma unroll
    for (int s = 0; s < 4; s++)
        out[(size_t)(tn + ty + s * 8) * K + tk + tx] = f2bf(tile[tx][ty + s * 8]);
}

extern "C" void kernel_launch(void* const* d_in, const int* in_sizes, int n_in,
                              void* d_out, int out_size, void* d_ws, size_t ws_size,
                              hipStream_t stream)
{
    const float* x  = (const float*)d_in[0];
    const float* wf = (const float*)d_in[1];
    const float* wg = (const float*)d_in[2];
    const float* wh = (const float*)d_in[3];
    const float* wo = (const float*)d_in[4];
    float* out = (float*)d_out;

    char* ws = (char*)d_ws;
    size_t off = 0;
    auto carve = [&](size_t bytes) {
        char* p = ws + off;
        off = (off + bytes + 255) & ~(size_t)255;
        return p;
    };
    unsigned short* xp   = (unsigned short*)carve(8ll * 1024 * 512 * 2);   // pooled, bf16
    unsigned short* wf_t = (unsigned short*)carve(64 * 512 * 2);
    unsigned short* wg_t = (unsigned short*)carve(64 * 512 * 2);
    unsigned short* wh_t = (unsigned short*)carve(256 * 512 * 2);
    unsigned short* wo_t = (unsigned short*)carve(512 * 256 * 2);
    unsigned short* gb   = (unsigned short*)carve(8ll * 1024 * 64 * 2);    // keys
    unsigned short* ht   = (unsigned short*)carve(8ll * 256 * 1024 * 2);   // values^T
    unsigned short* yb   = (unsigned short*)carve(8ll * 4096 * 256 * 2);

    // weight prep: all 4 transposes in one launch
    wprep<<<dim3(320), 256, 0, stream>>>(wf, wg, wh, wo, wf_t, wg_t, wh_t, wo_t);

    // pooled map (bf16)
    pool2<<<dim3(4096), 256, 0, stream>>>(x, xp);

    // g = xp @ wg   (flattened over batches)
    gemm_bt<1><<<dim3(1, 128, 1), 256, 0, stream>>>(xp, wg_t, gb, 8192, 64, 512, 0, 0, 0);
    // ht_b = wh^T @ xp_b^T  == (xp_b @ wh)^T  directly (no separate transpose)
    gemm_bt<1><<<dim3(16, 4, 8), 256, 0, stream>>>(wh_t, xp, ht, 256, 1024, 512,
                                                   0, 1024LL * 512, 256LL * 1024);

    // fused f-projection + attention: y = softmax((x wf) g^T) h
    flash_attn<<<dim3(256), 512, 0, stream>>>(x, wf_t, gb, ht, yb);

    // out = y @ wo  (fp32 store)
    gemm_bt<0><<<dim3(8, 512, 1), 256, 0, stream>>>(yb, wo_t, out, 32768, 512, 256, 0, 0, 0);
}

// Round 8
// 198.203 us; speedup vs baseline: 1.0296x; 1.0296x over previous
//
#include <hip/hip_runtime.h>
#include <hip/hip_bf16.h>

typedef __attribute__((ext_vector_type(8))) short bshort8;      // 8 bf16 (4 VGPR) MFMA frag
typedef __attribute__((ext_vector_type(4))) float f32x4;        // MFMA accumulator
typedef __attribute__((ext_vector_type(4))) float vfloat4;
typedef __attribute__((ext_vector_type(4))) unsigned int vuint4;
typedef __attribute__((ext_vector_type(2))) unsigned int vuint2;

__device__ __forceinline__ unsigned short f2bf(float f) {
    union { float f; unsigned u; } v; v.f = f;
    unsigned u = v.u;
    u += 0x7fffu + ((u >> 16) & 1u);   // round-to-nearest-even
    return (unsigned short)(u >> 16);
}

// ---------------------------------------------------------------------------
// gemm_bt: batched C = A[M][K] @ Bt[N][K]^T (bf16), 64x64 tile. Kept for the
// small g-projection (N=64). EPI: 0 = fp32 store, 1 = bf16 store
// ---------------------------------------------------------------------------
template<int EPI>
__global__ __launch_bounds__(256)
void gemm_bt(const unsigned short* __restrict__ Av, const unsigned short* __restrict__ Btv,
             void* __restrict__ Cv,
             int M, int N, int K,
             long long aB, long long bB, long long cB)
{
    __shared__ __align__(128) char sA[64 * 64];
    __shared__ __align__(128) char sB[64 * 64];

    const int b    = blockIdx.z;
    const int tid  = threadIdx.x;
    const int bRow = blockIdx.y << 6;
    const int bCol = blockIdx.x << 6;
    const int wid  = tid >> 6, lane = tid & 63;
    const int wr   = wid >> 1, wc   = wid & 1;
    const int r16  = lane & 15, kg  = lane >> 4;
    const int srow = tid >> 2,  skc = tid & 3;

    const unsigned short* A  = Av  + (size_t)aB * b;
    const unsigned short* Bt = Btv + (size_t)bB * b;

    f32x4 acc[2][2] = {};

    const size_t aRowBase = (size_t)(bRow + srow) * K + skc * 8;
    const size_t bRowBase = (size_t)(bCol + srow) * K + skc * 8;
    const unsigned swW = ((((unsigned)srow) << 6) | (((unsigned)skc) << 4))
                         ^ ((((unsigned)srow) & 7u) << 4);

    for (int k0 = 0; k0 < K; k0 += 32) {
        vuint4 apack = *(const vuint4*)(A  + aRowBase + k0);
        vuint4 bpack = *(const vuint4*)(Bt + bRowBase + k0);
        *(vuint4*)(sA + swW) = apack;
        *(vuint4*)(sB + swW) = bpack;
        __syncthreads();

        bshort8 af[2], bfr[2];
        #pragma unroll
        for (int mi = 0; mi < 2; mi++) {
            unsigned row = (unsigned)(wr * 32 + mi * 16 + r16);
            unsigned off = ((row << 6) | (((unsigned)kg) << 4)) ^ ((row & 7u) << 4);
            af[mi] = *(const bshort8*)(sA + off);
        }
        #pragma unroll
        for (int ni = 0; ni < 2; ni++) {
            unsigned col = (unsigned)(wc * 32 + ni * 16 + r16);
            unsigned off = ((col << 6) | (((unsigned)kg) << 4)) ^ ((col & 7u) << 4);
            bfr[ni] = *(const bshort8*)(sB + off);
        }
        #pragma unroll
        for (int mi = 0; mi < 2; mi++)
            #pragma unroll
            for (int ni = 0; ni < 2; ni++)
                acc[mi][ni] = __builtin_amdgcn_mfma_f32_16x16x32_bf16(
                                  af[mi], bfr[ni], acc[mi][ni], 0, 0, 0);
        __syncthreads();
    }

    #pragma unroll
    for (int mi = 0; mi < 2; mi++) {
        const int row0 = bRow + wr * 32 + mi * 16 + kg * 4;
        #pragma unroll
        for (int ni = 0; ni < 2; ni++) {
            const int col = bCol + wc * 32 + ni * 16 + r16;
            #pragma unroll
            for (int r = 0; r < 4; r++) {
                const int row = row0 + r;
                float x = acc[mi][ni][r];
                const size_t ci = (size_t)cB * b + (size_t)row * N + col;
                if constexpr (EPI == 0) ((float*)Cv)[ci] = x;
                else                    ((unsigned short*)Cv)[ci] = f2bf(x);
            }
        }
    }
}

// ---------------------------------------------------------------------------
// gemm_big: batched C = A[M][K] @ Bt[N][K]^T (bf16), 128x128 tile, BK=64,
// 512 threads / 8 waves (4 wr x 2 wc), wave tile 32x64 (acc 2x4).
// 16 MFMA per wave per K-step vs gemm_bt's 4 — 4x staging amortization.
// LDS 32KB -> 4 blocks/CU. EPI: 0 = fp32 store, 1 = bf16 store.
// Requires M%128==0, N%128==0, K%64==0.
// ---------------------------------------------------------------------------
template<int EPI>
__global__ __launch_bounds__(512)
void gemm_big(const unsigned short* __restrict__ Av, const unsigned short* __restrict__ Btv,
              void* __restrict__ Cv,
              int M, int N, int K,
              long long aB, long long bB, long long cB)
{
    __shared__ __align__(128) char sA[128 * 128];   // 128 rows x 64 bf16
    __shared__ __align__(128) char sB[128 * 128];

    const int b    = blockIdx.z;
    const int tid  = threadIdx.x;
    const int bRow = blockIdx.y << 7;
    const int bCol = blockIdx.x << 7;
    const int wid  = tid >> 6, lane = tid & 63;
    const int wr   = wid >> 1, wc   = wid & 1;
    const int r16  = lane & 15, kg  = lane >> 4;
    const int srow = tid >> 2,  sxc = tid & 3;      // staging: 128 rows, 4 thr/row

    const unsigned short* A  = Av  + (size_t)aB * b;
    const unsigned short* Bt = Btv + (size_t)bB * b;

    f32x4 acc[2][4] = {};

    const size_t aRowBase = (size_t)(bRow + srow) * K + sxc * 16;
    const size_t bRowBase = (size_t)(bCol + srow) * K + sxc * 16;
    const unsigned swz = (((unsigned)srow & 7u) << 4);
    const unsigned sw0 = ((unsigned)srow * 128 + (unsigned)sxc * 32) ^ swz;

    for (int k0 = 0; k0 < K; k0 += 64) {
        vuint4 a0 = *(const vuint4*)(A  + aRowBase + k0);
        vuint4 a1 = *(const vuint4*)(A  + aRowBase + k0 + 8);
        vuint4 b0 = *(const vuint4*)(Bt + bRowBase + k0);
        vuint4 b1 = *(const vuint4*)(Bt + bRowBase + k0 + 8);
        *(vuint4*)(sA + sw0)        = a0;
        *(vuint4*)(sA + (sw0 ^ 16)) = a1;    // +16B within 32B chunk: XOR-safe (bit4)
        *(vuint4*)(sB + sw0)        = b0;
        *(vuint4*)(sB + (sw0 ^ 16)) = b1;
        __syncthreads();

        bshort8 af[2][2], bf[4][2];
        #pragma unroll
        for (int mi = 0; mi < 2; mi++) {
            unsigned row = (unsigned)(wr * 32 + mi * 16 + r16);
            unsigned base = row * 128, sw = (row & 7u) << 4;
            af[mi][0] = *(const bshort8*)(sA + ((base + (unsigned)kg * 16) ^ sw));
            af[mi][1] = *(const bshort8*)(sA + ((base + 64 + (unsigned)kg * 16) ^ sw));
        }
        #pragma unroll
        for (int ni = 0; ni < 4; ni++) {
            unsigned col = (unsigned)(wc * 64 + ni * 16 + r16);
            unsigned base = col * 128, sw = (col & 7u) << 4;
            bf[ni][0] = *(const bshort8*)(sB + ((base + (unsigned)kg * 16) ^ sw));
            bf[ni][1] = *(const bshort8*)(sB + ((base + 64 + (unsigned)kg * 16) ^ sw));
        }
        #pragma unroll
        for (int mi = 0; mi < 2; mi++)
            #pragma unroll
            for (int ni = 0; ni < 4; ni++) {
                acc[mi][ni] = __builtin_amdgcn_mfma_f32_16x16x32_bf16(
                                  af[mi][0], bf[ni][0], acc[mi][ni], 0, 0, 0);
                acc[mi][ni] = __builtin_amdgcn_mfma_f32_16x16x32_bf16(
                                  af[mi][1], bf[ni][1], acc[mi][ni], 0, 0, 0);
            }
        __syncthreads();
    }

    // D frag: col = lane&15, row = (lane>>4)*4 + r  [verified layout]
    #pragma unroll
    for (int mi = 0; mi < 2; mi++) {
        const int row0 = bRow + wr * 32 + mi * 16 + kg * 4;
        #pragma unroll
        for (int ni = 0; ni < 4; ni++) {
            const int col = bCol + wc * 64 + ni * 16 + r16;
            #pragma unroll
            for (int r = 0; r < 4; r++) {
                const int row = row0 + r;
                float x = acc[mi][ni][r];
                const size_t ci = (size_t)cB * b + (size_t)row * N + col;
                if constexpr (EPI == 0) ((float*)Cv)[ci] = x;
                else                    ((unsigned short*)Cv)[ci] = f2bf(x);
            }
        }
    }
}

// ---------------------------------------------------------------------------
// Flash attention v5 (unchanged from round 7): swapped QK^T, wave-private P,
// 1 barrier/chunk, dbuf KV staging, setprio. LDS-BW-bound at ~51 us.
// ---------------------------------------------------------------------------
__global__ __launch_bounds__(512)
void flash_attn(const float* __restrict__ x,
                const unsigned short* __restrict__ wft,
                const unsigned short* __restrict__ gb,
                const unsigned short* __restrict__ ht,
                unsigned short* __restrict__ yb)
{
    __shared__ __align__(128) char sS[128 * 128];       // f tile / per-wave P (16KB)
    __shared__ __align__(128) char sG[2][64 * 128];     // g dbuf (16KB)
    __shared__ __align__(128) char sH[2][256 * 128];    // ht dbuf (64KB)

    const int tid = threadIdx.x;
    const int bid = blockIdx.x;
    const int b   = bid & 7;            // batch == XCD slot (L2-local KV)
    const int q0  = (bid >> 3) << 7;    // 128 q-rows per block
    const int wid = tid >> 6, lane = tid & 63;
    const int r16 = lane & 15, kg = lane >> 4;

    const float*          xB = x  + ((size_t)b * 4096 + q0) * 512;
    const unsigned short* gB = gb + (size_t)b * 1024 * 64;
    const unsigned short* hB = ht + (size_t)b * 256 * 1024;

    char* const sG0 = sG[0];
    char* const sH0 = sH[0];

    // ================= f = x @ wf  (128 x 64, K=512, BK=64) =================
    f32x4 facc[4] = {};
    {
        const int xrow = tid >> 2, xc = tid & 3;
        const int wrow = tid >> 3, wkc = tid & 7;
        const int frow = wid << 4;
        for (int k0 = 0; k0 < 512; k0 += 64) {
            {
                const float* p = xB + (size_t)xrow * 512 + k0 + xc * 16;
                #pragma unroll
                for (int j = 0; j < 2; j++) {
                    vfloat4 a0 = *(const vfloat4*)(p + j * 8);
                    vfloat4 a1 = *(const vfloat4*)(p + j * 8 + 4);
                    vuint4 w;
                    w[0] = (unsigned)f2bf(a0[0]) | ((unsigned)f2bf(a0[1]) << 16);
                    w[1] = (unsigned)f2bf(a0[2]) | ((unsigned)f2bf(a0[3]) << 16);
                    w[2] = (unsigned)f2bf(a1[0]) | ((unsigned)f2bf(a1[1]) << 16);
                    w[3] = (unsigned)f2bf(a1[2]) | ((unsigned)f2bf(a1[3]) << 16);
                    unsigned off = ((unsigned)xrow * 128 + (unsigned)(xc * 32 + j * 16))
                                   ^ (((unsigned)xrow & 7u) << 4);
                    *(vuint4*)(sH0 + off) = w;
                }
            }
            {
                vuint4 v = *(const vuint4*)(wft + (size_t)wrow * 512 + k0 + wkc * 8);
                unsigned off = ((unsigned)wrow * 128 + (unsigned)wkc * 16)
                               ^ (((unsigned)wrow & 7u) << 4);
                *(vuint4*)(sG0 + off) = v;
            }
            __syncthreads();

            bshort8 ax[2];
            {
                unsigned row = (unsigned)(frow + r16);
                unsigned base = row * 128, sw = (row & 7u) << 4;
                ax[0] = *(const bshort8*)(sH0 + ((base + (unsigned)kg * 16) ^ sw));
                ax[1] = *(const bshort8*)(sH0 + ((base + 64 + (unsigned)kg * 16) ^ sw));
            }
            #pragma unroll
            for (int ni = 0; ni < 4; ni++) {
                unsigned col = (unsigned)(ni * 16 + r16);
                unsigned base = col * 128, sw = (col & 7u) << 4;
                bshort8 b0 = *(const bshort8*)(sG0 + ((base + (unsigned)kg * 16) ^ sw));
                bshort8 b1 = *(const bshort8*)(sG0 + ((base + 64 + (unsigned)kg * 16) ^ sw));
                facc[ni] = __builtin_amdgcn_mfma_f32_16x16x32_bf16(ax[0], b0, facc[ni], 0, 0, 0);
                facc[ni] = __builtin_amdgcn_mfma_f32_16x16x32_bf16(ax[1], b1, facc[ni], 0, 0, 0);
            }
            __syncthreads();
        }

        const int frow2 = wid << 4;
        #pragma unroll
        for (int ni = 0; ni < 4; ni++) {
            const unsigned col = (unsigned)(ni * 16 + r16);
            #pragma unroll
            for (int r = 0; r < 4; r++) {
                unsigned row = (unsigned)(frow2 + kg * 4 + r);
                unsigned off = (row * 128 + col * 2) ^ ((row & 7u) << 4);
                *(unsigned short*)(sS + off) = f2bf(facc[ni][r]);
            }
        }
    }

    // ================= prologue: stage chunk 0 into buf 0 =================
    const int kc = tid & 7, n0 = tid >> 3;
    const unsigned gOff  = ((unsigned)n0 * 128 + (unsigned)kc * 16) ^ (((unsigned)n0 & 7u) << 4);
    const unsigned hOff0 = gOff;

    vuint4 gR, hR0, hR1, hR2, hR3;
    gR  = *(const vuint4*)(gB + (size_t)n0 * 64 + kc * 8);
    hR0 = *(const vuint4*)(hB + (size_t)(n0      ) * 1024 + kc * 8);
    hR1 = *(const vuint4*)(hB + (size_t)(n0 +  64) * 1024 + kc * 8);
    hR2 = *(const vuint4*)(hB + (size_t)(n0 + 128) * 1024 + kc * 8);
    hR3 = *(const vuint4*)(hB + (size_t)(n0 + 192) * 1024 + kc * 8);
    *(vuint4*)(sG0 + gOff)               = gR;
    *(vuint4*)(sH0 + hOff0)              = hR0;
    *(vuint4*)(sH0 + hOff0 +     8192)   = hR1;
    *(vuint4*)(sH0 + hOff0 + 2 * 8192)   = hR2;
    *(vuint4*)(sH0 + hOff0 + 3 * 8192)   = hR3;
    __syncthreads();

    char* const sP = sS + (wid << 11);
    bshort8 af[2];
    {
        unsigned base = (unsigned)r16 * 128, sw = ((unsigned)r16 & 7u) << 4;
        af[0] = *(const bshort8*)(sP + ((base + (unsigned)kg * 16) ^ sw));
        af[1] = *(const bshort8*)(sP + ((base + 64 + (unsigned)kg * 16) ^ sw));
    }

    // ================= KV loop (1 barrier/chunk, waves drift) =================
    f32x4 yacc[16] = {};
    float psum = 0.f;

    for (int c = 0; c < 16; c++) {
        const int cur = c & 1;
        char* const sGc = sG[cur];
        char* const sHc = sH[cur];

        if (c < 15) {
            const int kv1 = (c + 1) << 6;
            gR  = *(const vuint4*)(gB + (size_t)(kv1 + n0) * 64 + kc * 8);
            hR0 = *(const vuint4*)(hB + (size_t)(n0      ) * 1024 + kv1 + kc * 8);
            hR1 = *(const vuint4*)(hB + (size_t)(n0 +  64) * 1024 + kv1 + kc * 8);
            hR2 = *(const vuint4*)(hB + (size_t)(n0 + 128) * 1024 + kv1 + kc * 8);
            hR3 = *(const vuint4*)(hB + (size_t)(n0 + 192) * 1024 + kv1 + kc * 8);
        }

        f32x4 sacc[4] = {};
        {
            __builtin_amdgcn_s_setprio(1);
            #pragma unroll
            for (int kt = 0; kt < 4; kt++) {
                unsigned row = (unsigned)(kt * 16 + r16);
                unsigned base = row * 128, sw = (row & 7u) << 4;
                bshort8 g0 = *(const bshort8*)(sGc + ((base + (unsigned)kg * 16) ^ sw));
                bshort8 g1 = *(const bshort8*)(sGc + ((base + 64 + (unsigned)kg * 16) ^ sw));
                sacc[kt] = __builtin_amdgcn_mfma_f32_16x16x32_bf16(g0, af[0], sacc[kt], 0, 0, 0);
                sacc[kt] = __builtin_amdgcn_mfma_f32_16x16x32_bf16(g1, af[1], sacc[kt], 0, 0, 0);
            }
            __builtin_amdgcn_s_setprio(0);
        }

        #pragma unroll
        for (int kt = 0; kt < 4; kt++) {
            float e0 = __expf(sacc[kt][0]);
            float e1 = __expf(sacc[kt][1]);
            float e2 = __expf(sacc[kt][2]);
            float e3 = __expf(sacc[kt][3]);
            psum += (e0 + e1) + (e2 + e3);
            vuint2 pk;
            pk[0] = (unsigned)f2bf(e0) | ((unsigned)f2bf(e1) << 16);
            pk[1] = (unsigned)f2bf(e2) | ((unsigned)f2bf(e3) << 16);
            unsigned off = ((unsigned)r16 * 128 + (unsigned)(kt * 32 + kg * 8))
                           ^ (((unsigned)r16 & 7u) << 4);
            *(vuint2*)(sP + off) = pk;
        }

        bshort8 pa0, pa1;
        {
            unsigned base = (unsigned)r16 * 128, sw = ((unsigned)r16 & 7u) << 4;
            pa0 = *(const bshort8*)(sP + ((base + (unsigned)kg * 16) ^ sw));
            pa1 = *(const bshort8*)(sP + ((base + 64 + (unsigned)kg * 16) ^ sw));
        }
        __builtin_amdgcn_s_setprio(1);
        #pragma unroll
        for (int ni = 0; ni < 16; ni++) {
            unsigned col = (unsigned)(ni * 16 + r16);
            unsigned base = col * 128, sw = (col & 7u) << 4;
            bshort8 b0 = *(const bshort8*)(sHc + ((base + (unsigned)kg * 16) ^ sw));
            bshort8 b1 = *(const bshort8*)(sHc + ((base + 64 + (unsigned)kg * 16) ^ sw));
            yacc[ni] = __builtin_amdgcn_mfma_f32_16x16x32_bf16(pa0, b0, yacc[ni], 0, 0, 0);
            yacc[ni] = __builtin_amdgcn_mfma_f32_16x16x32_bf16(pa1, b1, yacc[ni], 0, 0, 0);
        }
        __builtin_amdgcn_s_setprio(0);

        if (c < 15) {
            char* const sGn = sG[cur ^ 1];
            char* const sHn = sH[cur ^ 1];
            *(vuint4*)(sGn + gOff)             = gR;
            *(vuint4*)(sHn + hOff0)            = hR0;
            *(vuint4*)(sHn + hOff0 +     8192) = hR1;
            *(vuint4*)(sHn + hOff0 + 2 * 8192) = hR2;
            *(vuint4*)(sHn + hOff0 + 3 * 8192) = hR3;
        }
        __syncthreads();
    }

    psum += __shfl_xor(psum, 16, 64);
    psum += __shfl_xor(psum, 32, 64);
    const float rinv = 1.0f / psum;

    unsigned short* yB = yb + ((size_t)b * 4096 + q0 + wid * 16) * 256;
    float rv[4];
    #pragma unroll
    for (int r = 0; r < 4; r++)
        rv[r] = __shfl(rinv, kg * 4 + r, 16);
    #pragma unroll
    for (int r = 0; r < 4; r++) {
        const int row = kg * 4 + r;
        #pragma unroll
        for (int ni = 0; ni < 16; ni++) {
            const int col = ni * 16 + r16;
            yB[(size_t)row * 256 + col] = f2bf(yacc[ni][r] * rv[r]);
        }
    }
}

// 2x2 avgpool NHWC fp32 -> bf16, 4 channels per thread
__global__ __launch_bounds__(256)
void pool2(const float* __restrict__ x, unsigned short* __restrict__ xp)
{
    const int t  = blockIdx.x * 256 + threadIdx.x;
    const int c4 = t & 127;
    const int j  = (t >> 7) & 31;
    const int i  = (t >> 12) & 31;
    const int b  = t >> 17;
    const float* p = x + ((((size_t)b * 64 + 2 * i) * 64) + 2 * j) * 512 + c4 * 4;
    vfloat4 a0 = *(const vfloat4*)p;
    vfloat4 a1 = *(const vfloat4*)(p + 512);
    vfloat4 a2 = *(const vfloat4*)(p + 64 * 512);
    vfloat4 a3 = *(const vfloat4*)(p + 64 * 512 + 512);
    float r0 = 0.25f * (a0[0] + a1[0] + a2[0] + a3[0]);
    float r1 = 0.25f * (a0[1] + a1[1] + a2[1] + a3[1]);
    float r2 = 0.25f * (a0[2] + a1[2] + a2[2] + a3[2]);
    float r3 = 0.25f * (a0[3] + a1[3] + a2[3] + a3[3]);
    vuint2 o;
    o[0] = (unsigned)f2bf(r0) | ((unsigned)f2bf(r1) << 16);
    o[1] = (unsigned)f2bf(r2) | ((unsigned)f2bf(r3) << 16);
    *(vuint2*)(xp + (size_t)t * 4) = o;
}

// All 4 weight transposes (fp32 [K][N] -> bf16 [N][K]) in ONE kernel.
__global__ __launch_bounds__(256)
void wprep(const float* __restrict__ wf, const float* __restrict__ wg,
           const float* __restrict__ wh, const float* __restrict__ wo,
           unsigned short* __restrict__ wf_t, unsigned short* __restrict__ wg_t,
           unsigned short* __restrict__ wh_t, unsigned short* __restrict__ wo_t)
{
    __shared__ float tile[32][33];
    int t = blockIdx.x;
    const float* in; unsigned short* out; int K, N;
    if (t < 32)       { in = wf; out = wf_t; K = 512; N = 64;  }
    else if (t < 64)  { in = wg; out = wg_t; K = 512; N = 64;  t -= 32;  }
    else if (t < 192) { in = wh; out = wh_t; K = 512; N = 256; t -= 64;  }
    else              { in = wo; out = wo_t; K = 256; N = 512; t -= 192; }
    const int ntN = N >> 5;
    const int tk = (t / ntN) << 5, tn = (t % ntN) << 5;
    const int tx = threadIdx.x & 31, ty = threadIdx.x >> 5;
    #pragma unroll
    for (int s = 0; s < 4; s++)
        tile[ty + s * 8][tx] = in[(size_t)(tk + ty + s * 8) * N + tn + tx];
    __syncthreads();
    #pragma unroll
    for (int s = 0; s < 4; s++)
        out[(size_t)(tn + ty + s * 8) * K + tk + tx] = f2bf(tile[tx][ty + s * 8]);
}

extern "C" void kernel_launch(void* const* d_in, const int* in_sizes, int n_in,
                              void* d_out, int out_size, void* d_ws, size_t ws_size,
                              hipStream_t stream)
{
    const float* x  = (const float*)d_in[0];
    const float* wf = (const float*)d_in[1];
    const float* wg = (const float*)d_in[2];
    const float* wh = (const float*)d_in[3];
    const float* wo = (const float*)d_in[4];
    float* out = (float*)d_out;

    char* ws = (char*)d_ws;
    size_t off = 0;
    auto carve = [&](size_t bytes) {
        char* p = ws + off;
        off = (off + bytes + 255) & ~(size_t)255;
        return p;
    };
    unsigned short* xp   = (unsigned short*)carve(8ll * 1024 * 512 * 2);   // pooled, bf16
    unsigned short* wf_t = (unsigned short*)carve(64 * 512 * 2);
    unsigned short* wg_t = (unsigned short*)carve(64 * 512 * 2);
    unsigned short* wh_t = (unsigned short*)carve(256 * 512 * 2);
    unsigned short* wo_t = (unsigned short*)carve(512 * 256 * 2);
    unsigned short* gb   = (unsigned short*)carve(8ll * 1024 * 64 * 2);    // keys
    unsigned short* ht   = (unsigned short*)carve(8ll * 256 * 1024 * 2);   // values^T
    unsigned short* yb   = (unsigned short*)carve(8ll * 4096 * 256 * 2);

    // weight prep: all 4 transposes in one launch
    wprep<<<dim3(320), 256, 0, stream>>>(wf, wg, wh, wo, wf_t, wg_t, wh_t, wo_t);

    // pooled map (bf16)
    pool2<<<dim3(4096), 256, 0, stream>>>(x, xp);

    // g = xp @ wg   (flattened over batches; N=64 -> small-tile gemm)
    gemm_bt<1><<<dim3(1, 128, 1), 256, 0, stream>>>(xp, wg_t, gb, 8192, 64, 512, 0, 0, 0);

    // ht_b = wh^T @ xp_b^T == (xp_b @ wh)^T : M=256, N=1024, K=512, 128^2 tile
    gemm_big<1><<<dim3(8, 2, 8), 512, 0, stream>>>(wh_t, xp, ht, 256, 1024, 512,
                                                   0, 1024LL * 512, 256LL * 1024);

    // fused f-projection + attention: y = softmax((x wf) g^T) h
    flash_attn<<<dim3(256), 512, 0, stream>>>(x, wf_t, gb, ht, yb);

    // out = y @ wo : M=32768, N=512, K=256, 128^2 tile (fp32 store)
    gemm_big<0><<<dim3(4, 256, 1), 512, 0, stream>>>(yb, wo_t, out, 32768, 512, 256,
                                                     0, 0, 0);
}